// Round 2
// baseline (1817.286 us; speedup 1.0000x reference)
//
#include <hip/hip_runtime.h>

#define NX 128
#define NSTEPS 4096

#if __has_builtin(__builtin_amdgcn_exp2f)
#define EXP2F(x) __builtin_amdgcn_exp2f(x)
#else
#define EXP2F(x) exp2f(x)
#endif
#if __has_builtin(__builtin_amdgcn_rcpf)
#define RCPF(x) __builtin_amdgcn_rcpf(x)
#else
#define RCPF(x) (1.0f / (x))
#endif

#if __has_builtin(__builtin_amdgcn_update_dpp)
template <int CTRL>
__device__ __forceinline__ float dpp_mov_f(float v) {
  int i = __float_as_int(v);
  return __int_as_float(__builtin_amdgcn_update_dpp(i, i, CTRL, 0xf, 0xf, false));
}
// reduce across the 8 lanes of a part-group; result valid on lanes with (lane&7)<4
// Stages 1-2: DPP quad_perm XOR involutions (direction-proof).
// Stage 3: shfl_xor(4) — row_ror direction on CDNA is lane i <- lane (i-n)%16,
// which crossed row-groups in the previous revision (the round-1 bug).
__device__ __forceinline__ float group8_reduce(float v) {
  v += dpp_mov_f<0xB1>(v);   // quad_perm [1,0,3,2]  (xor 1)
  v += dpp_mov_f<0x4E>(v);   // quad_perm [2,3,0,1]  (xor 2)
  v += __shfl_xor(v, 4, 64); // xor 4 (ds_swizzle, correct by definition)
  return v;
}
#else
__device__ __forceinline__ float group8_reduce(float v) {
  v += __shfl_xor(v, 1, 64);
  v += __shfl_xor(v, 2, 64);
  v += __shfl_xor(v, 4, 64);
  return v;
}
#endif

__launch_bounds__(256)
__global__ void nmpc_rollout_kernel(const float* __restrict__ x0,
                                    const float* __restrict__ xref,
                                    const float* __restrict__ useq,
                                    const float* __restrict__ A,
                                    const float* __restrict__ B,
                                    float* __restrict__ out) {
  __shared__ __align__(16) float lds_x[2][NX];
  __shared__ double wsum[4];

  const int t = threadIdx.x;
  const int g = t >> 3;       // row-group 0..31 (4 rows each)
  const int p = t & 7;        // column part 0..7 (16 cols each)
  const int pj = p & 3;       // row-within-group for tail lanes
  const int r = g * 4 + pj;   // valid row index for every lane (clamped via pj)
  const bool tail = (p < 4);

  // A fragment: rows g*4..g*4+3, cols p*16..p*16+15 -> 64 VGPRs
  float4 a[4][4];
#pragma unroll
  for (int j = 0; j < 4; ++j) {
#pragma unroll
    for (int q = 0; q < 4; ++q) {
      a[j][q] = *(const float4*)(A + (g * 4 + j) * NX + p * 16 + q * 4);
    }
  }

  const double b0 = (double)B[2 * r];
  const double b1 = (double)B[2 * r + 1];

  // fp64 state: dominant fp32 error was state-storage rounding (x grows to
  // O(100+); fp32 ulp ~3e-5/step random-walked over 4096 steps). State lives
  // in fp64 registers on tail lanes; LDS holds an fp32 copy for the matvec.
  double x_cur = (double)x0[r];
  double mse = 0.0;
  if (tail) {
    double d = x_cur - (double)xref[r];  // step-0 row of the trajectory
    mse = d * d;
    lds_x[0][r] = (float)x_cur;
  }
  __syncthreads();

  // software-pipelined prefetch of x_ref row (s+1) and u(s)
  float xr = xref[NX + r];
  float u0 = useq[0];
  float u1 = useq[NSTEPS];

  for (int s = 0; s < NSTEPS; ++s) {
    // ---- prefetch next step's operands (hidden under the FMA block) ----
    int nref = (s + 2 <= NSTEPS) ? (s + 2) : NSTEPS;
    float xr_next = xref[nref * NX + r];
    int nu = (s + 1 <= NSTEPS - 1) ? (s + 1) : (NSTEPS - 1);
    float u0_next = useq[nu];
    float u1_next = useq[NSTEPS + nu];

    // ---- read x slice from LDS (broadcast, conflict-free) ----
    const float4* xb = (const float4*)(&lds_x[s & 1][p * 16]);
    float4 xv[4];
    xv[0] = xb[0];
    xv[1] = xb[1];
    xv[2] = xb[2];
    xv[3] = xb[3];

    // ---- partial dot products: 4 rows x 16 cols ----
    float acc[4] = {0.f, 0.f, 0.f, 0.f};
#pragma unroll
    for (int q = 0; q < 4; ++q) {
#pragma unroll
      for (int j = 0; j < 4; ++j) {
        acc[j] = fmaf(a[j][q].x, xv[q].x, acc[j]);
        acc[j] = fmaf(a[j][q].y, xv[q].y, acc[j]);
        acc[j] = fmaf(a[j][q].z, xv[q].z, acc[j]);
        acc[j] = fmaf(a[j][q].w, xv[q].w, acc[j]);
      }
    }

    // ---- reduce across the 8 parts ----
#pragma unroll
    for (int j = 0; j < 4; ++j) acc[j] = group8_reduce(acc[j]);

    // lane pj selects its row's sum (static cndmask tree)
    float a01 = (p & 1) ? acc[1] : acc[0];
    float a23 = (p & 1) ? acc[3] : acc[2];
    float sum = (p & 2) ? a23 : a01;

    if (tail) {
      double z = (double)sum + b0 * (double)u0 + b1 * (double)u1;
      // branch-free tanh in f32 (abs error ~1e-7, subdominant): clamp, exp2
      float zf = (float)z;
      zf = fminf(fmaxf(zf, -15.f), 15.f);
      float e = EXP2F(zf * 2.8853900817779268f);  // 2*log2(e)
      float xd = (e - 1.f) * RCPF(e + 1.f);
      double xn = x_cur + (double)xd;
      x_cur = xn;
      lds_x[(s & 1) ^ 1][r] = (float)xn;
      double d = xn - (double)xr;
      mse += d * d;
    }
    __syncthreads();

    xr = xr_next;
    u0 = u0_next;
    u1 = u1_next;
  }

  // ---- final reduction of the MSE accumulator ----
#pragma unroll
  for (int off = 1; off < 64; off <<= 1) mse += __shfl_xor(mse, off, 64);
  if ((t & 63) == 0) wsum[t >> 6] = mse;
  __syncthreads();
  if (t == 0) {
    double tot = wsum[0] + wsum[1] + wsum[2] + wsum[3];
    out[0] = (float)(tot / (double)((NSTEPS + 1) * NX));
  }
}

extern "C" void kernel_launch(void* const* d_in, const int* in_sizes, int n_in,
                              void* d_out, int out_size, void* d_ws, size_t ws_size,
                              hipStream_t stream) {
  const float* x0 = (const float*)d_in[0];
  const float* xref = (const float*)d_in[1];
  const float* useq = (const float*)d_in[2];
  const float* A = (const float*)d_in[3];
  const float* B = (const float*)d_in[4];
  float* out = (float*)d_out;

  nmpc_rollout_kernel<<<dim3(1), dim3(256), 0, stream>>>(x0, xref, useq, A, B, out);
}